// Round 1
// baseline (73.214 us; speedup 1.0000x reference)
//
#include <hip/hip_runtime.h>

// ConvDeepSet: B=16, N=512, M=1024, CIN=7 (C=8 with ones-channel), COUT=64.
// out[b,m,o] = sum_c f(b,m,c) * W[o,c] + bias[o]
//   f[...,0]   = density  = sum_n exp(k_0 * d)
//   f[...,c>0] = (sum_n ctx[n,c] * exp(k_c * d)) / (density + 1e-8)
//   d = (context_in[b,n] - target_in[b,m])^2 ; k_c = -0.5 * exp(-2*sigma_c)

namespace {
constexpr int Bc   = 16;
constexpr int Nc   = 512;
constexpr int Mc   = 1024;
constexpr int CINc = 7;
constexpr int Cc   = 8;     // 1 + CIN
constexpr int CP   = 9;     // padded channel stride for the reduce buffer
constexpr int COUTc = 64;
constexpr int TM   = 32;    // m-values per block
constexpr int NCH  = 8;     // n-chunks per block
constexpr int NPC  = Nc / NCH;  // 64 n per chunk
constexpr int THREADS = TM * NCH;  // 256
constexpr float LOG2E = 1.4426950408889634f;
}

__global__ __launch_bounds__(THREADS) void convdeepset_kernel(
    const float* __restrict__ context_in,   // (B,N,1)
    const float* __restrict__ context_out,  // (B,N,CIN)
    const float* __restrict__ target_in,    // (B,M,1)
    const float* __restrict__ sigma,        // (C,)
    const float* __restrict__ W,            // (COUT,C)
    const float* __restrict__ bias,         // (COUT,)
    float* __restrict__ out)                // (B,M,COUT)
{
    __shared__ float s_ci[Nc];                 // context_in for this batch
    __shared__ float s_ctx[Nc * Cc];           // [n][c] ones-augmented context_out
    __shared__ float s_red[NCH][TM][CP];       // partial sums (padded: stride 9)
    __shared__ float s_tot[TM][Cc];            // reduced sums
    __shared__ float s_f[TM][Cc];              // density-normalized features
    __shared__ float s_Wt[Cc][COUTc];          // W transposed -> conflict-free epilogue
    __shared__ float s_bias[COUTc];
    __shared__ float s_k2[Cc];                 // k_c * log2(e)

    const int t   = threadIdx.x;
    const int blk = blockIdx.x;
    const int b   = blk / (Mc / TM);
    const int m0  = (blk % (Mc / TM)) * TM;

    // ---- stage constants ----
    if (t < COUTc) s_bias[t] = bias[t];
    if (t < Cc) {
        float s = sigma[t];
        float inv_sc2 = __builtin_amdgcn_exp2f(-2.0f * s * LOG2E);  // exp(-2*sigma) = 1/scale^2
        s_k2[t] = -0.5f * inv_sc2 * LOG2E;                          // base-2 exponent coefficient
    }
    for (int e = t; e < COUTc * Cc; e += THREADS) {
        int o = e / Cc, c = e % Cc;
        s_Wt[c][o] = W[e];
    }
    // ---- stage per-batch context ----
    for (int n = t; n < Nc; n += THREADS) {
        s_ci[n] = context_in[b * Nc + n];
        s_ctx[n * Cc + 0] = 1.0f;
    }
    for (int e = t; e < Nc * CINc; e += THREADS) {
        int n = e / CINc, c = e % CINc;
        s_ctx[n * Cc + 1 + c] = context_out[b * Nc * CINc + e];
    }
    __syncthreads();

    const int mi = t % TM;   // which m within the tile
    const int nc = t / TM;   // which n-chunk
    const float ti = target_in[b * Mc + m0 + mi];

    float k2[Cc];
    #pragma unroll
    for (int c = 0; c < Cc; c++) k2[c] = s_k2[c];
    bool uniform = true;
    #pragma unroll
    for (int c = 1; c < Cc; c++) uniform = uniform && (k2[c] == k2[0]);

    float acc[Cc];
    #pragma unroll
    for (int c = 0; c < Cc; c++) acc[c] = 0.0f;

    const int nbase = nc * NPC;
    if (uniform) {
        // All channel length-scales identical (the actual bench data): ONE exp per pair.
        const float k0 = k2[0];
        #pragma unroll 8
        for (int j = 0; j < NPC; j++) {
            const int n = nbase + j;
            const float diff = s_ci[n] - ti;
            const float w = __builtin_amdgcn_exp2f(k0 * diff * diff);
            const float4* p = (const float4*)&s_ctx[n * Cc];
            const float4 c0 = p[0], c1 = p[1];
            acc[0] += c0.x * w; acc[1] += c0.y * w; acc[2] += c0.z * w; acc[3] += c0.w * w;
            acc[4] += c1.x * w; acc[5] += c1.y * w; acc[6] += c1.z * w; acc[7] += c1.w * w;
        }
    } else {
        // General path: per-channel exponent.
        #pragma unroll 4
        for (int j = 0; j < NPC; j++) {
            const int n = nbase + j;
            const float diff = s_ci[n] - ti;
            const float d = diff * diff;
            const float4* p = (const float4*)&s_ctx[n * Cc];
            const float4 c0 = p[0], c1 = p[1];
            acc[0] += c0.x * __builtin_amdgcn_exp2f(k2[0] * d);
            acc[1] += c0.y * __builtin_amdgcn_exp2f(k2[1] * d);
            acc[2] += c0.z * __builtin_amdgcn_exp2f(k2[2] * d);
            acc[3] += c0.w * __builtin_amdgcn_exp2f(k2[3] * d);
            acc[4] += c1.x * __builtin_amdgcn_exp2f(k2[4] * d);
            acc[5] += c1.y * __builtin_amdgcn_exp2f(k2[5] * d);
            acc[6] += c1.z * __builtin_amdgcn_exp2f(k2[6] * d);
            acc[7] += c1.w * __builtin_amdgcn_exp2f(k2[7] * d);
        }
    }

    // ---- write partials (padded stride 9: stride-9 across lanes hits all 32 banks) ----
    #pragma unroll
    for (int c = 0; c < Cc; c++) s_red[nc][mi][c] = acc[c];
    __syncthreads();

    // ---- reduce over the 8 n-chunks: thread u owns (mi = u/8, c = u%8) ----
    {
        const int rmi = t >> 3;
        const int rc  = t & 7;
        float tot = 0.0f;
        #pragma unroll
        for (int k = 0; k < NCH; k++) tot += s_red[k][rmi][rc];
        s_tot[rmi][rc] = tot;
    }
    __syncthreads();
    {
        const int rmi = t >> 3;
        const int rc  = t & 7;
        const float tot  = s_tot[rmi][rc];
        const float dens = s_tot[rmi][0];
        s_f[rmi][rc] = (rc == 0) ? tot : tot / (dens + 1e-8f);
    }
    __syncthreads();

    // ---- epilogue: (TM x C) @ (C x COUT) + bias, coalesced stores ----
    const long long obase = (long long)(b * Mc + m0) * COUTc;
    #pragma unroll
    for (int r = 0; r < (TM * COUTc) / THREADS; r++) {
        const int flat = r * THREADS + t;
        const int o    = flat % COUTc;   // = lane -> coalesced, conflict-free Wt reads
        const int rmi  = flat / COUTc;   // wave-uniform -> broadcast s_f reads
        float v = s_bias[o];
        #pragma unroll
        for (int c = 0; c < Cc; c++) v += s_f[rmi][c] * s_Wt[c][o];
        out[obase + flat] = v;
    }
}

extern "C" void kernel_launch(void* const* d_in, const int* in_sizes, int n_in,
                              void* d_out, int out_size, void* d_ws, size_t ws_size,
                              hipStream_t stream) {
    const float* context_in  = (const float*)d_in[0];
    const float* context_out = (const float*)d_in[1];
    const float* target_in   = (const float*)d_in[2];
    const float* sigma       = (const float*)d_in[3];
    const float* W           = (const float*)d_in[4];
    const float* bias        = (const float*)d_in[5];
    float* out = (float*)d_out;

    const int grid = Bc * (Mc / TM);  // 512 blocks, 256 threads each
    convdeepset_kernel<<<grid, THREADS, 0, stream>>>(
        context_in, context_out, target_in, sigma, W, bias, out);
}

// Round 2
// 69.936 us; speedup vs baseline: 1.0469x; 1.0469x over previous
//
#include <hip/hip_runtime.h>

// ConvDeepSet: B=16, N=512, M=1024, CIN=7 (C=8 with ones-channel), COUT=64.
// out[b,m,o] = sum_c f(b,m,c) * W[o,c] + bias[o]
//   f[...,0]   = density  = sum_n exp(k_0 * d)
//   f[...,c>0] = (sum_n ctx[n,c] * exp(k_c * d)) / (density + 1e-8)
//   d = (context_in[b,n] - target_in[b,m])^2 ; k_c = -0.5 * exp(-2*sigma_c)
//
// LDS record per n: [ci, x1..x7]  (ci sits in the ones-channel slot; density
// just accumulates w directly, so the "1.0" is never multiplied).

namespace {
constexpr int Bc    = 16;
constexpr int Nc    = 512;
constexpr int Mc    = 1024;
constexpr int CINc  = 7;
constexpr int Cc    = 8;      // 1 + CIN
constexpr int CP    = 9;      // padded channel stride for the reduce buffer
constexpr int COUTc = 64;
constexpr int TM    = 32;     // m-values per block
constexpr int NCH   = 16;     // n-chunks per block
constexpr int NPC   = Nc / NCH;       // 32 n per chunk
constexpr int THREADS = TM * NCH;     // 512 -> 8 waves/block, 2 blocks/CU, 4 waves/SIMD
constexpr float LOG2E = 1.4426950408889634f;
}

__global__ __launch_bounds__(THREADS) void convdeepset_kernel(
    const float* __restrict__ context_in,   // (B,N,1)
    const float* __restrict__ context_out,  // (B,N,CIN)
    const float* __restrict__ target_in,    // (B,M,1)
    const float* __restrict__ sigma,        // (C,)
    const float* __restrict__ W,            // (COUT,C)
    const float* __restrict__ bias,         // (COUT,)
    float* __restrict__ out)                // (B,M,COUT)
{
    __shared__ float s_ctx[Nc * Cc];           // [n][0]=ci, [n][1+c]=context_out
    __shared__ float s_red[NCH][TM][CP];       // partial sums (padded stride 9)
    __shared__ float s_tot[TM][Cc];
    __shared__ float s_f[TM][Cc];
    __shared__ float s_Wt[Cc][COUTc];
    __shared__ float s_bias[COUTc];
    __shared__ float s_k2[Cc];                 // k_c * log2(e)

    const int t   = threadIdx.x;
    const int blk = blockIdx.x;
    const int b   = blk / (Mc / TM);
    const int m0  = (blk % (Mc / TM)) * TM;

    // ---- stage constants ----
    if (t < COUTc) s_bias[t] = bias[t];
    if (t < Cc) {
        float s = sigma[t];
        float inv_sc2 = __builtin_amdgcn_exp2f(-2.0f * s * LOG2E);  // exp(-2*sigma)
        s_k2[t] = -0.5f * inv_sc2 * LOG2E;
    }
    if (t < COUTc * Cc) {               // 512 threads == 512 elements of W
        int o = t / Cc, c = t % Cc;
        s_Wt[c][o] = W[t];
    }
    // ---- stage per-batch context ----
    {
        const int n = t;                // THREADS == Nc
        s_ctx[n * Cc] = context_in[b * Nc + n];
    }
    #pragma unroll
    for (int r = 0; r < (Nc * CINc) / THREADS; r++) {   // 7 iters, exact
        int e = r * THREADS + t;
        int n = e / CINc, c = e % CINc;
        s_ctx[n * Cc + 1 + c] = context_out[b * Nc * CINc + e];
    }
    __syncthreads();

    const int mi  = t % TM;   // m within tile
    const int ncq = t / TM;   // n-chunk
    const float ti = target_in[b * Mc + m0 + mi];

    float k2[Cc];
    #pragma unroll
    for (int c = 0; c < Cc; c++) k2[c] = s_k2[c];
    bool uniform = true;
    #pragma unroll
    for (int c = 1; c < Cc; c++) uniform = uniform && (k2[c] == k2[0]);

    float acc[Cc];
    #pragma unroll
    for (int c = 0; c < Cc; c++) acc[c] = 0.0f;

    const int nbase = ncq * NPC;
    if (uniform) {
        // All channel length-scales identical (actual bench data): ONE exp per pair.
        const float k0 = k2[0];
        #pragma unroll 8
        for (int j = 0; j < NPC; j++) {
            const float4* p = (const float4*)&s_ctx[(nbase + j) * Cc];
            const float4 c0 = p[0], c1 = p[1];      // c0.x = ci
            const float diff = c0.x - ti;
            const float w = __builtin_amdgcn_exp2f((k0 * diff) * diff);
            acc[0] += w;
            acc[1] += c0.y * w; acc[2] += c0.z * w; acc[3] += c0.w * w;
            acc[4] += c1.x * w; acc[5] += c1.y * w; acc[6] += c1.z * w; acc[7] += c1.w * w;
        }
    } else {
        #pragma unroll 4
        for (int j = 0; j < NPC; j++) {
            const float4* p = (const float4*)&s_ctx[(nbase + j) * Cc];
            const float4 c0 = p[0], c1 = p[1];
            const float diff = c0.x - ti;
            const float d = diff * diff;
            acc[0] += __builtin_amdgcn_exp2f(k2[0] * d);
            acc[1] += c0.y * __builtin_amdgcn_exp2f(k2[1] * d);
            acc[2] += c0.z * __builtin_amdgcn_exp2f(k2[2] * d);
            acc[3] += c0.w * __builtin_amdgcn_exp2f(k2[3] * d);
            acc[4] += c1.x * __builtin_amdgcn_exp2f(k2[4] * d);
            acc[5] += c1.y * __builtin_amdgcn_exp2f(k2[5] * d);
            acc[6] += c1.z * __builtin_amdgcn_exp2f(k2[6] * d);
            acc[7] += c1.w * __builtin_amdgcn_exp2f(k2[7] * d);
        }
    }

    // ---- write partials (stride-9 across lanes -> all 32 banks, <=2-way) ----
    #pragma unroll
    for (int c = 0; c < Cc; c++) s_red[ncq][mi][c] = acc[c];
    __syncthreads();

    // ---- reduce over 16 n-chunks: thread u<256 owns (mi=u/8, c=u%8) ----
    if (t < TM * Cc) {
        const int rmi = t >> 3;
        const int rc  = t & 7;
        float tot = 0.0f;
        #pragma unroll
        for (int k = 0; k < NCH; k++) tot += s_red[k][rmi][rc];
        s_tot[rmi][rc] = tot;
    }
    __syncthreads();
    if (t < TM * Cc) {
        const int rmi = t >> 3;
        const int rc  = t & 7;
        const float tot  = s_tot[rmi][rc];
        const float dens = s_tot[rmi][0];
        s_f[rmi][rc] = (rc == 0) ? tot : tot / (dens + 1e-8f);
    }
    __syncthreads();

    // ---- epilogue: (TM x C) @ (C x COUT) + bias, coalesced stores ----
    const long long obase = (long long)(b * Mc + m0) * COUTc;
    #pragma unroll
    for (int r = 0; r < (TM * COUTc) / THREADS; r++) {   // 4 iters
        const int flat = r * THREADS + t;
        const int o    = flat % COUTc;   // = lane -> coalesced, conflict-free
        const int rmi  = flat / COUTc;   // wave-uniform -> LDS broadcast
        float v = s_bias[o];
        #pragma unroll
        for (int c = 0; c < Cc; c++) v += s_f[rmi][c] * s_Wt[c][o];
        out[obase + flat] = v;
    }
}

extern "C" void kernel_launch(void* const* d_in, const int* in_sizes, int n_in,
                              void* d_out, int out_size, void* d_ws, size_t ws_size,
                              hipStream_t stream) {
    const float* context_in  = (const float*)d_in[0];
    const float* context_out = (const float*)d_in[1];
    const float* target_in   = (const float*)d_in[2];
    const float* sigma       = (const float*)d_in[3];
    const float* W           = (const float*)d_in[4];
    const float* bias        = (const float*)d_in[5];
    float* out = (float*)d_out;

    const int grid = Bc * (Mc / TM);  // 512 blocks x 512 threads
    convdeepset_kernel<<<grid, THREADS, 0, stream>>>(
        context_in, context_out, target_in, sigma, W, bias, out);
}